// Round 4
// baseline (179.556 us; speedup 1.0000x reference)
//
#include <hip/hip_runtime.h>

// PyramidToDepth: x (8,512,512,2) fp32 -> out (8,18,512,512,1) fp32
// levels lv=0..8, S=512>>lv; out[b, 2*lv+c, h, w] = bilinear_up(level_lv)[b,h,w,c]
//
// d_ws holds levels 1..8, channel-interleaved (B,S,S,2), float2-unit offsets:
//   lv:    1       2       3       4       5       6       7       8
//   off2:  0  524288  655360  688128  696320  698368  698880  699008

#define HWTOT (512 * 512)

typedef float vfloat4 __attribute__((ext_vector_type(4)));

__constant__ int c_off2[9] = {0, 0, 524288, 655360, 688128, 696320, 698368, 698880, 699008};

// --- Kernel A: levels 1..6, one block per 64x64 input tile -------------------
__global__ __launch_bounds__(256) void build_levels_1_6(const float* __restrict__ x,
                                                        float2* __restrict__ pyr) {
  const int b = blockIdx.y;
  const int tx = blockIdx.x & 7, ty = blockIdx.x >> 3;
  const int t = threadIdx.x;

  __shared__ float2 sh1[32 * 32];
  __shared__ float2 sh2[16 * 16];
  __shared__ float2 sh3[8 * 8];
  __shared__ float2 sh4[4 * 4];
  __shared__ float2 sh5[2 * 2];

  // level 1: 32x32 tile-local, 4 consecutive cols per thread
  {
    const int i = t >> 3;
    const int j0 = (t & 7) << 2;
    const float* r0 = x + (((size_t)(b * 512 + ty * 64 + 2 * i)) * 512 + (tx * 64 + 2 * j0)) * 2;
    const float* r1 = r0 + 1024;
    float2 o[4];
#pragma unroll
    for (int k = 0; k < 4; ++k) {
      float4 a = *(const float4*)(r0 + 4 * k);
      float4 c = *(const float4*)(r1 + 4 * k);
      o[k].x = (a.x + a.z + c.x + c.z) * 0.25f;
      o[k].y = (a.y + a.w + c.y + c.w) * 0.25f;
      sh1[i * 32 + j0 + k] = o[k];
    }
    float2* g = pyr + ((size_t)(b * 256 + ty * 32 + i) * 256 + tx * 32 + j0);
    *(float4*)(g) = make_float4(o[0].x, o[0].y, o[1].x, o[1].y);
    *(float4*)(g + 2) = make_float4(o[2].x, o[2].y, o[3].x, o[3].y);
  }
  __syncthreads();
  // level 2: 16x16
  {
    const int i = t >> 4, j = t & 15;
    float2 a = sh1[(2 * i) * 32 + 2 * j], c = sh1[(2 * i) * 32 + 2 * j + 1];
    float2 d = sh1[(2 * i + 1) * 32 + 2 * j], e = sh1[(2 * i + 1) * 32 + 2 * j + 1];
    float2 o = {(a.x + c.x + d.x + e.x) * 0.25f, (a.y + c.y + d.y + e.y) * 0.25f};
    sh2[i * 16 + j] = o;
    pyr[524288 + (size_t)(b * 128 + ty * 16 + i) * 128 + tx * 16 + j] = o;
  }
  __syncthreads();
  // level 3: 8x8
  if (t < 64) {
    const int i = t >> 3, j = t & 7;
    float2 a = sh2[(2 * i) * 16 + 2 * j], c = sh2[(2 * i) * 16 + 2 * j + 1];
    float2 d = sh2[(2 * i + 1) * 16 + 2 * j], e = sh2[(2 * i + 1) * 16 + 2 * j + 1];
    float2 o = {(a.x + c.x + d.x + e.x) * 0.25f, (a.y + c.y + d.y + e.y) * 0.25f};
    sh3[i * 8 + j] = o;
    pyr[655360 + (size_t)(b * 64 + ty * 8 + i) * 64 + tx * 8 + j] = o;
  }
  __syncthreads();
  // level 4: 4x4
  if (t < 16) {
    const int i = t >> 2, j = t & 3;
    float2 a = sh3[(2 * i) * 8 + 2 * j], c = sh3[(2 * i) * 8 + 2 * j + 1];
    float2 d = sh3[(2 * i + 1) * 8 + 2 * j], e = sh3[(2 * i + 1) * 8 + 2 * j + 1];
    float2 o = {(a.x + c.x + d.x + e.x) * 0.25f, (a.y + c.y + d.y + e.y) * 0.25f};
    sh4[i * 4 + j] = o;
    pyr[688128 + (size_t)(b * 32 + ty * 4 + i) * 32 + tx * 4 + j] = o;
  }
  __syncthreads();
  // level 5: 2x2
  if (t < 4) {
    const int i = t >> 1, j = t & 1;
    float2 a = sh4[(2 * i) * 4 + 2 * j], c = sh4[(2 * i) * 4 + 2 * j + 1];
    float2 d = sh4[(2 * i + 1) * 4 + 2 * j], e = sh4[(2 * i + 1) * 4 + 2 * j + 1];
    float2 o = {(a.x + c.x + d.x + e.x) * 0.25f, (a.y + c.y + d.y + e.y) * 0.25f};
    sh5[i * 2 + j] = o;
    pyr[696320 + (size_t)(b * 16 + ty * 2 + i) * 16 + tx * 2 + j] = o;
  }
  __syncthreads();
  // level 6: 1x1
  if (t == 0) {
    float2 a = sh5[0], c = sh5[1], d = sh5[2], e = sh5[3];
    float2 o = {(a.x + c.x + d.x + e.x) * 0.25f, (a.y + c.y + d.y + e.y) * 0.25f};
    pyr[698368 + (size_t)(b * 8 + ty) * 8 + tx] = o;
  }
}

// --- Kernel B: levels 7..8 from level 6, one block per image -----------------
__global__ __launch_bounds__(64) void build_levels_7_8(float2* __restrict__ pyr) {
  const int b = blockIdx.x;
  const int t = threadIdx.x;
  __shared__ float2 s7[16];
  const float2* l6 = pyr + 698368 + (size_t)b * 64;
  if (t < 16) {
    const int i = t >> 2, j = t & 3;
    float2 a = l6[(2 * i) * 8 + 2 * j], c = l6[(2 * i) * 8 + 2 * j + 1];
    float2 d = l6[(2 * i + 1) * 8 + 2 * j], e = l6[(2 * i + 1) * 8 + 2 * j + 1];
    float2 o = {(a.x + c.x + d.x + e.x) * 0.25f, (a.y + c.y + d.y + e.y) * 0.25f};
    s7[t] = o;
    pyr[698880 + (size_t)b * 16 + t] = o;
  }
  __syncthreads();
  if (t < 4) {
    const int i = t >> 1, j = t & 1;
    float2 a = s7[(2 * i) * 4 + 2 * j], c = s7[(2 * i) * 4 + 2 * j + 1];
    float2 d = s7[(2 * i + 1) * 4 + 2 * j], e = s7[(2 * i + 1) * 4 + 2 * j + 1];
    float2 o = {(a.x + c.x + d.x + e.x) * 0.25f, (a.y + c.y + d.y + e.y) * 0.25f};
    pyr[699008 + (size_t)b * 4 + t] = o;
  }
}

// --- Kernel C: one LEVEL per block (blockIdx.z), 4 w-px per thread -----------
// Short 1-deep VMEM chain per thread; 9x the waves for latency hiding.
__global__ __launch_bounds__(256) void upsample_lv(const float* __restrict__ x,
                                                   const float2* __restrict__ pyr,
                                                   float* __restrict__ out) {
  const int t = threadIdx.x;
  const int w0pix = (t & 127) << 2;            // 4 consecutive w
  const int h = (blockIdx.x << 1) + (t >> 7);  // wave-uniform
  const int b = blockIdx.y;
  const int lv = blockIdx.z;  // 0..8, wave-uniform
  const size_t obase = (size_t)(b * 18 + 2 * lv) * HWTOT + (size_t)h * 512 + w0pix;

  if (lv == 0) {  // identity resize
    const float* px = x + (((size_t)b * 512 + h) * 512 + w0pix) * 2;
    float4 a = *(const float4*)px;
    float4 c = *(const float4*)(px + 4);
    vfloat4 ch0 = {a.x, a.z, c.x, c.z};
    vfloat4 ch1 = {a.y, a.w, c.y, c.w};
    __builtin_nontemporal_store(ch0, (vfloat4*)(out + obase));
    __builtin_nontemporal_store(ch1, (vfloat4*)(out + obase + HWTOT));
    return;
  }

  const int S = 512 >> lv;
  const float scale = 1.0f / (float)(1 << lv);
  // jax.image.resize bilinear = half-pixel centers + clamp-to-edge
  float sh = ((float)h + 0.5f) * scale - 0.5f;
  float fh0f = floorf(sh);
  float fh = sh - fh0f;
  int h0 = (int)fh0f;
  int h0c = h0 < 0 ? 0 : h0;
  int h1c = (h0 + 1 > S - 1) ? (S - 1) : (h0 + 1);
  const float2* R0 = pyr + c_off2[lv] + (size_t)(b * S + h0c) * S;
  const float2* R1 = pyr + c_off2[lv] + (size_t)(b * S + h1c) * S;
  const float wy0 = 1.0f - fh;

  float o0[4], o1[4];
#pragma unroll
  for (int k = 0; k < 4; ++k) {
    float sw = ((float)(w0pix + k) + 0.5f) * scale - 0.5f;
    float fw0f = floorf(sw);
    float fw = sw - fw0f;
    int w0 = (int)fw0f;
    int w0c = w0 < 0 ? 0 : w0;
    int w1c = (w0 + 1 > S - 1) ? (S - 1) : (w0 + 1);
    float2 v00 = R0[w0c], v01 = R0[w1c];
    float2 v10 = R1[w0c], v11 = R1[w1c];
    float wx0 = 1.0f - fw;
    float tx_ = v00.x * wx0 + v01.x * fw;
    float bx_ = v10.x * wx0 + v11.x * fw;
    float ty_ = v00.y * wx0 + v01.y * fw;
    float by_ = v10.y * wx0 + v11.y * fw;
    o0[k] = tx_ * wy0 + bx_ * fh;
    o1[k] = ty_ * wy0 + by_ * fh;
  }
  vfloat4 c0 = {o0[0], o0[1], o0[2], o0[3]};
  vfloat4 c1 = {o1[0], o1[1], o1[2], o1[3]};
  __builtin_nontemporal_store(c0, (vfloat4*)(out + obase));
  __builtin_nontemporal_store(c1, (vfloat4*)(out + obase + HWTOT));
}

extern "C" void kernel_launch(void* const* d_in, const int* in_sizes, int n_in,
                              void* d_out, int out_size, void* d_ws, size_t ws_size,
                              hipStream_t stream) {
  const float* x = (const float*)d_in[0];
  float* out = (float*)d_out;
  float2* pyr = (float2*)d_ws;

  build_levels_1_6<<<dim3(64, 8), 256, 0, stream>>>(x, pyr);
  build_levels_7_8<<<dim3(8), 64, 0, stream>>>(pyr);
  upsample_lv<<<dim3(256, 8, 9), 256, 0, stream>>>(x, pyr, out);
}

// Round 5
// 175.949 us; speedup vs baseline: 1.0205x; 1.0205x over previous
//
#include <hip/hip_runtime.h>

// PyramidToDepth: x (8,512,512,2) fp32 -> out (8,18,512,512,1) fp32
// levels lv=0..8, S=512>>lv; out[b, 2*lv+c, h, w] = bilinear_up(level_lv)[b,h,w,c]
//
// d_ws holds levels 1..6, channel-interleaved (B,S,S,2), float2-unit offsets:
//   lv:    1       2       3       4       5       6
//   off2:  0  524288  655360  688128  696320  698368
// Levels 7..8 are rebuilt per-block in LDS by the upsample kernel (from lv6).

#define HWTOT (512 * 512)

typedef float vfloat4 __attribute__((ext_vector_type(4)));

__constant__ int c_off2[7] = {0, 0, 524288, 655360, 688128, 696320, 698368};

// --- Kernel A: levels 1..6, one block per 64x64 input tile -------------------
__global__ __launch_bounds__(256) void build_levels_1_6(const float* __restrict__ x,
                                                        float2* __restrict__ pyr) {
  const int b = blockIdx.y;
  const int tx = blockIdx.x & 7, ty = blockIdx.x >> 3;
  const int t = threadIdx.x;

  __shared__ float2 sh1[32 * 32];
  __shared__ float2 sh2[16 * 16];
  __shared__ float2 sh3[8 * 8];
  __shared__ float2 sh4[4 * 4];
  __shared__ float2 sh5[2 * 2];

  // level 1: 32x32 tile-local, 4 consecutive cols per thread
  {
    const int i = t >> 3;
    const int j0 = (t & 7) << 2;
    const float* r0 = x + (((size_t)(b * 512 + ty * 64 + 2 * i)) * 512 + (tx * 64 + 2 * j0)) * 2;
    const float* r1 = r0 + 1024;
    float2 o[4];
#pragma unroll
    for (int k = 0; k < 4; ++k) {
      float4 a = *(const float4*)(r0 + 4 * k);
      float4 c = *(const float4*)(r1 + 4 * k);
      o[k].x = (a.x + a.z + c.x + c.z) * 0.25f;
      o[k].y = (a.y + a.w + c.y + c.w) * 0.25f;
      sh1[i * 32 + j0 + k] = o[k];
    }
    float2* g = pyr + ((size_t)(b * 256 + ty * 32 + i) * 256 + tx * 32 + j0);
    *(float4*)(g) = make_float4(o[0].x, o[0].y, o[1].x, o[1].y);
    *(float4*)(g + 2) = make_float4(o[2].x, o[2].y, o[3].x, o[3].y);
  }
  __syncthreads();
  // level 2: 16x16
  {
    const int i = t >> 4, j = t & 15;
    float2 a = sh1[(2 * i) * 32 + 2 * j], c = sh1[(2 * i) * 32 + 2 * j + 1];
    float2 d = sh1[(2 * i + 1) * 32 + 2 * j], e = sh1[(2 * i + 1) * 32 + 2 * j + 1];
    float2 o = {(a.x + c.x + d.x + e.x) * 0.25f, (a.y + c.y + d.y + e.y) * 0.25f};
    sh2[i * 16 + j] = o;
    pyr[524288 + (size_t)(b * 128 + ty * 16 + i) * 128 + tx * 16 + j] = o;
  }
  __syncthreads();
  // level 3: 8x8
  if (t < 64) {
    const int i = t >> 3, j = t & 7;
    float2 a = sh2[(2 * i) * 16 + 2 * j], c = sh2[(2 * i) * 16 + 2 * j + 1];
    float2 d = sh2[(2 * i + 1) * 16 + 2 * j], e = sh2[(2 * i + 1) * 16 + 2 * j + 1];
    float2 o = {(a.x + c.x + d.x + e.x) * 0.25f, (a.y + c.y + d.y + e.y) * 0.25f};
    sh3[i * 8 + j] = o;
    pyr[655360 + (size_t)(b * 64 + ty * 8 + i) * 64 + tx * 8 + j] = o;
  }
  __syncthreads();
  // level 4: 4x4
  if (t < 16) {
    const int i = t >> 2, j = t & 3;
    float2 a = sh3[(2 * i) * 8 + 2 * j], c = sh3[(2 * i) * 8 + 2 * j + 1];
    float2 d = sh3[(2 * i + 1) * 8 + 2 * j], e = sh3[(2 * i + 1) * 8 + 2 * j + 1];
    float2 o = {(a.x + c.x + d.x + e.x) * 0.25f, (a.y + c.y + d.y + e.y) * 0.25f};
    sh4[i * 4 + j] = o;
    pyr[688128 + (size_t)(b * 32 + ty * 4 + i) * 32 + tx * 4 + j] = o;
  }
  __syncthreads();
  // level 5: 2x2
  if (t < 4) {
    const int i = t >> 1, j = t & 1;
    float2 a = sh4[(2 * i) * 4 + 2 * j], c = sh4[(2 * i) * 4 + 2 * j + 1];
    float2 d = sh4[(2 * i + 1) * 4 + 2 * j], e = sh4[(2 * i + 1) * 4 + 2 * j + 1];
    float2 o = {(a.x + c.x + d.x + e.x) * 0.25f, (a.y + c.y + d.y + e.y) * 0.25f};
    sh5[i * 2 + j] = o;
    pyr[696320 + (size_t)(b * 16 + ty * 2 + i) * 16 + tx * 2 + j] = o;
  }
  __syncthreads();
  // level 6: 1x1
  if (t == 0) {
    float2 a = sh5[0], c = sh5[1], d = sh5[2], e = sh5[3];
    float2 o = {(a.x + c.x + d.x + e.x) * 0.25f, (a.y + c.y + d.y + e.y) * 0.25f};
    pyr[698368 + (size_t)(b * 8 + ty) * 8 + tx] = o;
  }
}

// --- Kernel C: one LEVEL per block (blockIdx.z = lv, block-uniform). ---------
// lv 0: copy of x. lv 1..6: bilinear gather from pyramid. lv 7..8: rebuild the
// tiny lv7/lv8 image in LDS from lv6 (same rounding chain as iterative pool),
// then bilinear from LDS. Plain (non-NT) float4 stores.
__global__ __launch_bounds__(256) void upsample_lv(const float* __restrict__ x,
                                                   const float2* __restrict__ pyr,
                                                   float* __restrict__ out) {
  const int t = threadIdx.x;
  const int w0pix = (t & 127) << 2;            // 4 consecutive w
  const int h = (blockIdx.x << 1) + (t >> 7);  // wave-uniform
  const int b = blockIdx.y;
  const int lv = blockIdx.z;  // 0..8, block-uniform
  const size_t obase = (size_t)(b * 18 + 2 * lv) * HWTOT + (size_t)h * 512 + w0pix;

  if (lv == 0) {  // identity resize
    const float* px = x + (((size_t)b * 512 + h) * 512 + w0pix) * 2;
    float4 a = *(const float4*)px;
    float4 c = *(const float4*)(px + 4);
    *(vfloat4*)(out + obase) = (vfloat4){a.x, a.z, c.x, c.z};
    *(vfloat4*)(out + obase + HWTOT) = (vfloat4){a.y, a.w, c.y, c.w};
    return;
  }

  __shared__ float2 stage[20];  // [0..15] = lv7 (4x4), [16..19] = lv8 (2x2)

  const int S = 512 >> lv;
  const float scale = 1.0f / (float)(1 << lv);

  const float2* img;  // S x S source image rows
  if (lv <= 6) {
    img = pyr + c_off2[lv] + (size_t)b * S * S;
  } else {
    // rebuild lv7 (and lv8) from lv6 in LDS; block-uniform branch -> sync safe
    const float2* l6 = pyr + 698368 + (size_t)b * 64;
    if (t < 16) {
      const int i = t >> 2, j = t & 3;
      float2 a = l6[(2 * i) * 8 + 2 * j], c = l6[(2 * i) * 8 + 2 * j + 1];
      float2 d = l6[(2 * i + 1) * 8 + 2 * j], e = l6[(2 * i + 1) * 8 + 2 * j + 1];
      stage[t] = {(a.x + c.x + d.x + e.x) * 0.25f, (a.y + c.y + d.y + e.y) * 0.25f};
    }
    __syncthreads();
    if (lv == 8 && t < 4) {
      const int i = t >> 1, j = t & 1;
      float2 a = stage[(2 * i) * 4 + 2 * j], c = stage[(2 * i) * 4 + 2 * j + 1];
      float2 d = stage[(2 * i + 1) * 4 + 2 * j], e = stage[(2 * i + 1) * 4 + 2 * j + 1];
      stage[16 + t] = {(a.x + c.x + d.x + e.x) * 0.25f, (a.y + c.y + d.y + e.y) * 0.25f};
    }
    __syncthreads();
    img = (lv == 7) ? (const float2*)stage : (const float2*)(stage + 16);
  }

  // jax.image.resize bilinear = half-pixel centers + clamp-to-edge
  float sh = ((float)h + 0.5f) * scale - 0.5f;
  float fh0f = floorf(sh);
  float fh = sh - fh0f;
  int h0 = (int)fh0f;
  int h0c = h0 < 0 ? 0 : h0;
  int h1c = (h0 + 1 > S - 1) ? (S - 1) : (h0 + 1);
  const float2* R0 = img + (size_t)h0c * S;
  const float2* R1 = img + (size_t)h1c * S;
  const float wy0 = 1.0f - fh;

  float o0[4], o1[4];
#pragma unroll
  for (int k = 0; k < 4; ++k) {
    float sw = ((float)(w0pix + k) + 0.5f) * scale - 0.5f;
    float fw0f = floorf(sw);
    float fw = sw - fw0f;
    int w0 = (int)fw0f;
    int w0c = w0 < 0 ? 0 : w0;
    int w1c = (w0 + 1 > S - 1) ? (S - 1) : (w0 + 1);
    float2 v00 = R0[w0c], v01 = R0[w1c];
    float2 v10 = R1[w0c], v11 = R1[w1c];
    float wx0 = 1.0f - fw;
    float tx_ = v00.x * wx0 + v01.x * fw;
    float bx_ = v10.x * wx0 + v11.x * fw;
    float ty_ = v00.y * wx0 + v01.y * fw;
    float by_ = v10.y * wx0 + v11.y * fw;
    o0[k] = tx_ * wy0 + bx_ * fh;
    o1[k] = ty_ * wy0 + by_ * fh;
  }
  *(vfloat4*)(out + obase) = (vfloat4){o0[0], o0[1], o0[2], o0[3]};
  *(vfloat4*)(out + obase + HWTOT) = (vfloat4){o1[0], o1[1], o1[2], o1[3]};
}

extern "C" void kernel_launch(void* const* d_in, const int* in_sizes, int n_in,
                              void* d_out, int out_size, void* d_ws, size_t ws_size,
                              hipStream_t stream) {
  const float* x = (const float*)d_in[0];
  float* out = (float*)d_out;
  float2* pyr = (float2*)d_ws;

  build_levels_1_6<<<dim3(64, 8), 256, 0, stream>>>(x, pyr);
  upsample_lv<<<dim3(256, 8, 9), 256, 0, stream>>>(x, pyr, out);
}